// Round 4
// baseline (281.830 us; speedup 1.0000x reference)
//
#include <hip/hip_runtime.h>
#include <hip/hip_bf16.h>

#define NROW 8192
#define NDIM 256
#define INV_T (1.0f / 0.07f)
#define K_BOT 819      // first selected descending rank
#define K_TOP 4095     // one past last selected rank
#define N_SEL 3276
#define N_UNSEL 4916   // 8192 - N_SEL (includes diagonal at -10)

typedef unsigned int u32;
typedef unsigned short u16;
typedef short s16;
typedef unsigned long long u64;
typedef __bf16 bf16_t;
typedef s16 s16x8 __attribute__((ext_vector_type(8)));
typedef float f32x4 __attribute__((ext_vector_type(4)));

__device__ __forceinline__ u16 bfbits(float f) {
    return __builtin_bit_cast(u16, (bf16_t)f);   // RNE f32->bf16, raw bits
}
// order-preserving bf16-bits -> u16 key (bigger float <=> bigger key)
__device__ __forceinline__ u16 map16(u16 b) {
    return (b & 0x8000u) ? (u16)~b : (u16)(b | 0x8000u);
}
__device__ __forceinline__ float unmap16(u32 m) {
    u16 b = (m & 0x8000u) ? (u16)(m & 0x7FFFu) : (u16)~(u16)m;
    return __uint_as_float(((u32)b) << 16);
}

__device__ __forceinline__ void gload16(const void* g, void* l) {
    __builtin_amdgcn_global_load_lds(
        (const __attribute__((address_space(1))) u32*)g,
        (__attribute__((address_space(3))) u32*)l, 16, 0, 0);
}

// ---------------- fp32 -> bf16 (both inputs, one launch) ----------------
__global__ __launch_bounds__(256) void cvt_bf16(const float* __restrict__ in0,
                                                const float* __restrict__ in1,
                                                u16* __restrict__ out0,
                                                u16* __restrict__ out1) {
    int b = blockIdx.x;
    const float* in = (b < 2048) ? in0 : in1;
    u16* out = (b < 2048) ? out0 : out1;
    int i = ((b & 2047) * 256 + threadIdx.x) * 4;
    float4 v = *(const float4*)(in + i);
    ushort4 o;
    o.x = bfbits(v.x); o.y = bfbits(v.y); o.z = bfbits(v.z); o.w = bfbits(v.w);
    *(ushort4*)(out + i) = o;
}

// ---------------- GEMM: keys = map16(bf16(Q @ K^T)) ----------------
// 128x128 tile, BK=64, 4 waves (2x2), wave = 64x64 via 4x4 frags of 16x16x32.
// Staging via global_load_lds dwordx4 with source-side chunk swizzle (rule #21).
// Diagonal tiles write the rank sentinel key 0 at (r,r).
__global__ __launch_bounds__(256) void gemm_keys(const u16* __restrict__ Qb,
                                                 const u16* __restrict__ Kb,
                                                 u16* __restrict__ Cp) {
    constexpr int BK = 64;
    __shared__ __align__(16) char smem[128 * 132 * 2];   // 33792 B (union)
    u16* sA = (u16*)smem;                    // [128][64] bf16
    u16* sB = (u16*)(smem + 128 * BK * 2);   // [128][64]
    u16* sC = (u16*)smem;                    // [128][132] epilogue transpose

    const int tid  = threadIdx.x;
    const int lane = tid & 63;
    const int wid  = tid >> 6;
    const int wr = wid >> 1, wc = wid & 1;
    const int bm = blockIdx.y * 128;
    const int bn = blockIdx.x * 128;
    const int kg = lane >> 4;
    const int fr = lane & 15;

    // staging: segment = 8 rows x 128B; lane l -> row seg*8 + (l>>3),
    // LDS chunk jp = l&7 holds source chunk j = jp ^ (row&7).
    const int srr = lane >> 3;
    const int srj = (lane & 7) ^ srr;

    f32x4 acc[4][4] = {};

    for (int k0 = 0; k0 < NDIM; k0 += BK) {
        __syncthreads();
#pragma unroll
        for (int s = 0; s < 4; ++s) {
            int seg = wid * 4 + s;                // 0..15
            int row = seg * 8 + srr;
            gload16(Qb + (size_t)(bm + row) * NDIM + k0 + srj * 8, &sA[seg * 512]);
            gload16(Kb + (size_t)(bn + row) * NDIM + k0 + srj * 8, &sB[seg * 512]);
        }
        __syncthreads();

#pragma unroll
        for (int kk = 0; kk < 2; ++kk) {
            s16x8 af[4], bfv[4];
#pragma unroll
            for (int m = 0; m < 4; ++m) {
                int row = wr * 64 + m * 16 + fr;
                int jp = (kk * 4 + kg) ^ (fr & 7);
                af[m] = *(const s16x8*)(&sA[row * BK + jp * 8]);
            }
#pragma unroll
            for (int n = 0; n < 4; ++n) {
                int row = wc * 64 + n * 16 + fr;
                int jp = (kk * 4 + kg) ^ (fr & 7);
                bfv[n] = *(const s16x8*)(&sB[row * BK + jp * 8]);
            }
#pragma unroll
            for (int m = 0; m < 4; ++m)
#pragma unroll
                for (int n = 0; n < 4; ++n)
                    acc[m][n] = __builtin_amdgcn_mfma_f32_16x16x32_bf16(
                        af[m], bfv[n], acc[m][n], 0, 0, 0);
        }
    }

    __syncthreads();   // done reading sA/sB; reuse LDS as sC
#pragma unroll
    for (int m = 0; m < 4; ++m)
#pragma unroll
        for (int n = 0; n < 4; ++n)
#pragma unroll
            for (int jj = 0; jj < 4; ++jj) {
                int r = wr * 64 + m * 16 + kg * 4 + jj;   // C/D: row = (lane>>4)*4+reg
                int c = wc * 64 + n * 16 + fr;            //      col = lane&15
                sC[r * 132 + c] = map16(bfbits(acc[m][n][jj]));
            }
    __syncthreads();
    if (bm == bn) {                      // diagonal tile: sentinel key 0 at (r,r)
        if (tid < 128) sC[tid * 132 + tid] = 0;
        __syncthreads();
    }
#pragma unroll
    for (int it = 0; it < 8; ++it) {
        int c = it * 256 + tid;                   // 16B chunk index, 0..2047
        int row = c >> 4, col8 = (c & 15) * 8;
        *(uint4*)(&Cp[(size_t)(bm + row) * NROW + bn + col8]) =
            *(const uint4*)(&sC[row * 132 + col8]);
    }
}

// ---------------- per-row rank select + LSE, register-resident ----------------
__global__ __launch_bounds__(256) void rank_lse(const u16* __restrict__ Cp,
                                                const float* __restrict__ fq,
                                                const float* __restrict__ fk,
                                                float* __restrict__ loss) {
    const int row = blockIdx.x;
    const int t = threadIdx.x;
    const int w = t >> 6;
    __shared__ u32 wred[2][4];
    __shared__ float warr[4];
    __shared__ float wsum[4];
    __shared__ u32 wcnt[4][3];

    // 32 keys per thread, unpacked into registers
    const u16* rowp = Cp + (size_t)row * NROW;
    u32 k[32];
#pragma unroll
    for (int i = 0; i < 4; ++i) {
        uint4 v = *(const uint4*)(rowp + i * 2048 + t * 8);
        k[i * 8 + 0] = v.x & 0xFFFFu; k[i * 8 + 1] = v.x >> 16;
        k[i * 8 + 2] = v.y & 0xFFFFu; k[i * 8 + 3] = v.y >> 16;
        k[i * 8 + 4] = v.z & 0xFFFFu; k[i * 8 + 5] = v.z >> 16;
        k[i * 8 + 6] = v.w & 0xFFFFu; k[i * 8 + 7] = v.w >> 16;
    }

    // exact fp32 l_pos
    float p = fq[(size_t)row * NDIM + t] * fk[(size_t)row * NDIM + t];
#pragma unroll
    for (int o = 32; o; o >>= 1) p += __shfl_down(p, o);
    if ((t & 63) == 0) warr[w] = p;
    __syncthreads();
    const float lp = (warr[0] + warr[1]) + (warr[2] + warr[3]);

    // ballot bisection for rank K_BOT (A) and rank K_TOP-1 (B)
    u32 loA = 0, hiA = 65535, loB = 0, hiB = 65535;
#pragma unroll 1
    for (int it = 0; it < 16; ++it) {
        const u32 mA = (loA + hiA) >> 1;
        const u32 mB = (loB + hiB) >> 1;
        u32 cA = 0, cB = 0;
#pragma unroll
        for (int j = 0; j < 32; ++j) {
            cA += (u32)__popcll(__ballot(k[j] > mA));
            cB += (u32)__popcll(__ballot(k[j] > mB));
        }
        if ((t & 63) == 0) wred[it & 1][w] = (cA << 16) | cB;
        __syncthreads();
        const u32 s = wred[it & 1][0] + wred[it & 1][1]
                    + wred[it & 1][2] + wred[it & 1][3];
        const u32 CA = s >> 16, CB = s & 0xFFFFu;
        if (CA <= (u32)K_BOT)       hiA = mA; else loA = mA + 1;
        if (CB <= (u32)(K_TOP - 1)) hiB = mB; else loB = mB + 1;
    }
    const u32 ua = loA, ub = loB;

    // tie-exact window sum + LSE
    const float a  = unmap16(ua);
    const float bv = unmap16(ub);
    const float m_ = fmaxf(fmaxf(lp, a), -10.0f) * INV_T;

    u32 cga = 0, cea = 0, cgb = 0;   // wave totals via ballot
    float sm = 0.f;
#pragma unroll
    for (int j = 0; j < 32; ++j) {
        u32 u = k[j];
        cga += (u32)__popcll(__ballot(u > ua));
        cea += (u32)__popcll(__ballot(u == ua));
        cgb += (u32)__popcll(__ballot(u > ub));
        if (u < ua && u > ub) sm += __expf(unmap16(u) * INV_T - m_);
    }
#pragma unroll
    for (int o = 32; o; o >>= 1) sm += __shfl_down(sm, o);
    if ((t & 63) == 0) {
        wsum[w] = sm;
        wcnt[w][0] = cga; wcnt[w][1] = cea; wcnt[w][2] = cgb;
    }
    __syncthreads();
    if (t == 0) {
        float S = (wsum[0] + wsum[1]) + (wsum[2] + wsum[3]);
        u32 Ga = wcnt[0][0] + wcnt[1][0] + wcnt[2][0] + wcnt[3][0];
        u32 Ea = wcnt[0][1] + wcnt[1][1] + wcnt[2][1] + wcnt[3][1];
        u32 Gb = wcnt[0][2] + wcnt[1][2] + wcnt[2][2] + wcnt[3][2];
        float expA = __expf(a * INV_T - m_);
        float tot;
        if (ua == ub) {
            tot = (float)N_SEL * expA;
        } else {
            float expB = __expf(bv * INV_T - m_);
            tot = S + (float)(int)(Ga + Ea - (u32)K_BOT) * expA
                    + (float)(int)((u32)K_TOP - Gb) * expB;
        }
        tot += __expf(lp * INV_T - m_) + (float)N_UNSEL * __expf(-10.0f * INV_T - m_);
        loss[row] = m_ + __logf(tot) - lp * INV_T;
    }
}

// ---------------- host ----------------
extern "C" void kernel_launch(void* const* d_in, const int* in_sizes, int n_in,
                              void* d_out, int out_size, void* d_ws, size_t ws_size,
                              hipStream_t stream) {
    const float* fq = (const float*)d_in[0];
    const float* fk = (const float*)d_in[1];
    float* out = (float*)d_out;

    char* ws = (char*)d_ws;
    u16* keys = (u16*)ws;                                  // 128 MiB
    u16* qb = (u16*)(ws + (size_t)NROW * NROW * 2);        // 4 MiB
    u16* kb = qb + (size_t)NROW * NDIM;                    // 4 MiB

    cvt_bf16<<<4096, 256, 0, stream>>>(fq, fk, qb, kb);
    gemm_keys<<<dim3(NROW / 128, NROW / 128), 256, 0, stream>>>(qb, kb, keys);
    rank_lse<<<NROW, 256, 0, stream>>>(keys, fq, fk, out);
}

// Round 5
// 264.418 us; speedup vs baseline: 1.0659x; 1.0659x over previous
//
#include <hip/hip_runtime.h>
#include <hip/hip_bf16.h>

#define NROW 8192
#define NDIM 256
#define INV_T (1.0f / 0.07f)
#define K_BOT 819      // first selected descending rank
#define K_TOP 4095     // one past last selected rank
#define N_SEL 3276
#define N_UNSEL 4916   // 8192 - N_SEL (includes diagonal at -10)

typedef unsigned int u32;
typedef unsigned short u16;
typedef short s16;
typedef unsigned long long u64;
typedef __bf16 bf16_t;
typedef s16 s16x8 __attribute__((ext_vector_type(8)));
typedef float f32x4 __attribute__((ext_vector_type(4)));

__device__ __forceinline__ u16 bfbits(float f) {
    return __builtin_bit_cast(u16, (bf16_t)f);   // RNE f32->bf16, raw bits
}
// order-preserving bf16-bits -> u16 key (bigger float <=> bigger key)
__device__ __forceinline__ u16 map16(u16 b) {
    return (b & 0x8000u) ? (u16)~b : (u16)(b | 0x8000u);
}
__device__ __forceinline__ float unmap16(u32 m) {
    u16 b = (m & 0x8000u) ? (u16)(m & 0x7FFFu) : (u16)~(u16)m;
    return __uint_as_float(((u32)b) << 16);
}

__device__ __forceinline__ void gload16(const void* g, void* l) {
    __builtin_amdgcn_global_load_lds(
        (const __attribute__((address_space(1))) u32*)g,
        (__attribute__((address_space(3))) u32*)l, 16, 0, 0);
}

// ---------------- fp32 -> bf16 (both inputs, one launch) ----------------
__global__ __launch_bounds__(256) void cvt_bf16(const float* __restrict__ in0,
                                                const float* __restrict__ in1,
                                                u16* __restrict__ out0,
                                                u16* __restrict__ out1) {
    int b = blockIdx.x;
    const float* in = (b < 2048) ? in0 : in1;
    u16* out = (b < 2048) ? out0 : out1;
    int i = ((b & 2047) * 256 + threadIdx.x) * 4;
    float4 v = *(const float4*)(in + i);
    ushort4 o;
    o.x = bfbits(v.x); o.y = bfbits(v.y); o.z = bfbits(v.z); o.w = bfbits(v.w);
    *(ushort4*)(out + i) = o;
}

// ---------------- GEMM: keys = map16(bf16(Q @ K^T)) ----------------
// 128x128 tile, BK=64, 4 waves (2x2), wave = 64x64 via 4x4 frags of 16x16x32.
// Staging via global_load_lds dwordx4 with source-side chunk swizzle (rule #21).
// Diagonal tiles write the rank sentinel key 0 at (r,r).
__global__ __launch_bounds__(256) void gemm_keys(const u16* __restrict__ Qb,
                                                 const u16* __restrict__ Kb,
                                                 u16* __restrict__ Cp) {
    constexpr int BK = 64;
    __shared__ __align__(16) char smem[128 * 132 * 2];   // 33792 B (union)
    u16* sA = (u16*)smem;                    // [128][64] bf16
    u16* sB = (u16*)(smem + 128 * BK * 2);   // [128][64]
    u16* sC = (u16*)smem;                    // [128][132] epilogue transpose

    const int tid  = threadIdx.x;
    const int lane = tid & 63;
    const int wid  = tid >> 6;
    const int wr = wid >> 1, wc = wid & 1;
    const int bm = blockIdx.y * 128;
    const int bn = blockIdx.x * 128;
    const int kg = lane >> 4;
    const int fr = lane & 15;

    // staging: segment = 8 rows x 128B; lane l -> row seg*8 + (l>>3),
    // LDS chunk jp = l&7 holds source chunk j = jp ^ (row&7).
    const int srr = lane >> 3;
    const int srj = (lane & 7) ^ srr;

    f32x4 acc[4][4] = {};

    for (int k0 = 0; k0 < NDIM; k0 += BK) {
        __syncthreads();
#pragma unroll
        for (int s = 0; s < 4; ++s) {
            int seg = wid * 4 + s;                // 0..15
            int row = seg * 8 + srr;
            gload16(Qb + (size_t)(bm + row) * NDIM + k0 + srj * 8, &sA[seg * 512]);
            gload16(Kb + (size_t)(bn + row) * NDIM + k0 + srj * 8, &sB[seg * 512]);
        }
        __syncthreads();

#pragma unroll
        for (int kk = 0; kk < 2; ++kk) {
            s16x8 af[4], bfv[4];
#pragma unroll
            for (int m = 0; m < 4; ++m) {
                int row = wr * 64 + m * 16 + fr;
                int jp = (kk * 4 + kg) ^ (fr & 7);
                af[m] = *(const s16x8*)(&sA[row * BK + jp * 8]);
            }
#pragma unroll
            for (int n = 0; n < 4; ++n) {
                int row = wc * 64 + n * 16 + fr;
                int jp = (kk * 4 + kg) ^ (fr & 7);
                bfv[n] = *(const s16x8*)(&sB[row * BK + jp * 8]);
            }
#pragma unroll
            for (int m = 0; m < 4; ++m)
#pragma unroll
                for (int n = 0; n < 4; ++n)
                    acc[m][n] = __builtin_amdgcn_mfma_f32_16x16x32_bf16(
                        af[m], bfv[n], acc[m][n], 0, 0, 0);
        }
    }

    __syncthreads();   // done reading sA/sB; reuse LDS as sC
#pragma unroll
    for (int m = 0; m < 4; ++m)
#pragma unroll
        for (int n = 0; n < 4; ++n)
#pragma unroll
            for (int jj = 0; jj < 4; ++jj) {
                int r = wr * 64 + m * 16 + kg * 4 + jj;   // C/D: row = (lane>>4)*4+reg
                int c = wc * 64 + n * 16 + fr;            //      col = lane&15
                sC[r * 132 + c] = map16(bfbits(acc[m][n][jj]));
            }
    __syncthreads();
    if (bm == bn) {                      // diagonal tile: sentinel key 0 at (r,r)
        if (tid < 128) sC[tid * 132 + tid] = 0;
        __syncthreads();
    }
#pragma unroll
    for (int it = 0; it < 8; ++it) {
        int c = it * 256 + tid;                   // 16B chunk index, 0..2047
        int row = c >> 4, col8 = (c & 15) * 8;
        *(uint4*)(&Cp[(size_t)(bm + row) * NROW + bn + col8]) =
            *(const uint4*)(&sC[row * 132 + col8]);
    }
}

// ---------------- per-row rank select + LSE, register-resident ----------------
__global__ __launch_bounds__(256) void rank_lse(const u16* __restrict__ Cp,
                                                const float* __restrict__ fq,
                                                const float* __restrict__ fk,
                                                float* __restrict__ loss) {
    const int row = blockIdx.x;
    const int t = threadIdx.x;
    const int w = t >> 6;
    __shared__ u32 wred[2][4];
    __shared__ float warr[4];
    __shared__ float wsum[4];
    __shared__ u32 wcnt[4][3];

    // 32 keys per thread, unpacked ONCE into registers and pinned there
    const u16* rowp = Cp + (size_t)row * NROW;
    u32 k[32];
#pragma unroll
    for (int i = 0; i < 4; ++i) {
        uint4 v = *(const uint4*)(rowp + i * 2048 + t * 8);
        k[i * 8 + 0] = v.x & 0xFFFFu; k[i * 8 + 1] = v.x >> 16;
        k[i * 8 + 2] = v.y & 0xFFFFu; k[i * 8 + 3] = v.y >> 16;
        k[i * 8 + 4] = v.z & 0xFFFFu; k[i * 8 + 5] = v.z >> 16;
        k[i * 8 + 6] = v.w & 0xFFFFu; k[i * 8 + 7] = v.w >> 16;
    }
    // pin: compiler may not rematerialize these from memory (round-4 bug:
    // VGPR_Count=24 proved it re-loaded+re-unpacked in every bisect iter)
#pragma unroll
    for (int j = 0; j < 32; ++j) asm volatile("" : "+v"(k[j]));

    // exact fp32 l_pos
    float p = fq[(size_t)row * NDIM + t] * fk[(size_t)row * NDIM + t];
#pragma unroll
    for (int o = 32; o; o >>= 1) p += __shfl_down(p, o);
    if ((t & 63) == 0) warr[w] = p;
    __syncthreads();
    const float lp = (warr[0] + warr[1]) + (warr[2] + warr[3]);

    // ballot bisection for rank K_BOT (A) and rank K_TOP-1 (B)
    u32 loA = 0, hiA = 65535, loB = 0, hiB = 65535;
#pragma unroll 1
    for (int it = 0; it < 16; ++it) {
        const u32 mA = (loA + hiA) >> 1;
        const u32 mB = (loB + hiB) >> 1;
        u32 cA = 0, cB = 0;
        if (loA < hiA) {                 // block-uniform guard
#pragma unroll
            for (int j = 0; j < 32; ++j)
                cA += (u32)__popcll(__ballot(k[j] > mA));
        }
        if (loB < hiB) {
#pragma unroll
            for (int j = 0; j < 32; ++j)
                cB += (u32)__popcll(__ballot(k[j] > mB));
        }
        if ((t & 63) == 0) wred[it & 1][w] = (cA << 16) | cB;
        __syncthreads();
        const u32 s = wred[it & 1][0] + wred[it & 1][1]
                    + wred[it & 1][2] + wred[it & 1][3];
        if (loA < hiA) {
            const u32 CA = s >> 16;
            if (CA <= (u32)K_BOT) hiA = mA; else loA = mA + 1;
        }
        if (loB < hiB) {
            const u32 CB = s & 0xFFFFu;
            if (CB <= (u32)(K_TOP - 1)) hiB = mB; else loB = mB + 1;
        }
        if (loA >= hiA && loB >= hiB) break;   // uniform across block
    }
    const u32 ua = loA, ub = loB;

    // tie-exact window sum + LSE
    const float a  = unmap16(ua);
    const float bv = unmap16(ub);
    const float m_ = fmaxf(fmaxf(lp, a), -10.0f) * INV_T;

    u32 cga = 0, cea = 0, cgb = 0;   // wave totals via ballot
    float sm = 0.f;
#pragma unroll
    for (int j = 0; j < 32; ++j) {
        u32 u = k[j];
        cga += (u32)__popcll(__ballot(u > ua));
        cea += (u32)__popcll(__ballot(u == ua));
        cgb += (u32)__popcll(__ballot(u > ub));
        if (u < ua && u > ub) sm += __expf(unmap16(u) * INV_T - m_);
    }
#pragma unroll
    for (int o = 32; o; o >>= 1) sm += __shfl_down(sm, o);
    if ((t & 63) == 0) {
        wsum[w] = sm;
        wcnt[w][0] = cga; wcnt[w][1] = cea; wcnt[w][2] = cgb;
    }
    __syncthreads();
    if (t == 0) {
        float S = (wsum[0] + wsum[1]) + (wsum[2] + wsum[3]);
        u32 Ga = wcnt[0][0] + wcnt[1][0] + wcnt[2][0] + wcnt[3][0];
        u32 Ea = wcnt[0][1] + wcnt[1][1] + wcnt[2][1] + wcnt[3][1];
        u32 Gb = wcnt[0][2] + wcnt[1][2] + wcnt[2][2] + wcnt[3][2];
        float expA = __expf(a * INV_T - m_);
        float tot;
        if (ua == ub) {
            tot = (float)N_SEL * expA;
        } else {
            float expB = __expf(bv * INV_T - m_);
            tot = S + (float)(int)(Ga + Ea - (u32)K_BOT) * expA
                    + (float)(int)((u32)K_TOP - Gb) * expB;
        }
        tot += __expf(lp * INV_T - m_) + (float)N_UNSEL * __expf(-10.0f * INV_T - m_);
        loss[row] = m_ + __logf(tot) - lp * INV_T;
    }
}

// ---------------- host ----------------
extern "C" void kernel_launch(void* const* d_in, const int* in_sizes, int n_in,
                              void* d_out, int out_size, void* d_ws, size_t ws_size,
                              hipStream_t stream) {
    const float* fq = (const float*)d_in[0];
    const float* fk = (const float*)d_in[1];
    float* out = (float*)d_out;

    char* ws = (char*)d_ws;
    u16* keys = (u16*)ws;                                  // 128 MiB
    u16* qb = (u16*)(ws + (size_t)NROW * NROW * 2);        // 4 MiB
    u16* kb = qb + (size_t)NROW * NDIM;                    // 4 MiB

    cvt_bf16<<<4096, 256, 0, stream>>>(fq, fk, qb, kb);
    gemm_keys<<<dim3(NROW / 128, NROW / 128), 256, 0, stream>>>(qb, kb, keys);
    rank_lse<<<NROW, 256, 0, stream>>>(keys, fq, fk, out);
}